// Round 8
// baseline (436.134 us; speedup 1.0000x reference)
//
#include <hip/hip_runtime.h>
#include <math.h>

typedef __attribute__((ext_vector_type(8))) short short8;
typedef __attribute__((ext_vector_type(4))) float f32x4;
typedef __attribute__((ext_vector_type(4))) unsigned int u32x4;

#define BB 2
#define TT 6
#define PP 20480
#define EPSc 1e-5f

// ws layout (bytes), all 16B aligned
#define WS_WIN   0u          // in_proj frags   [68][64] short8 = 69632
#define WS_WOF   69632u      // 0.5*nwf*Wout    [24][64] short8 = 24576
#define WS_WOB   94208u      // 0.5*nwb*Wout    [24][64] short8 = 24576
#define WS_W1    118784u     // mlp_w1 frags    [18][64] short8 = 18432
#define WS_W2    137216u     // mlp_w2 frags    [18][64] short8 = 18432
#define WS_EW    155648u     // embed frags(+eb row) [2][64] = 2048
#define WS_L1    157696u     // loan1 frags(+b row)  [8][64] = 8192
#define WS_L2    165888u     // loan2 frags(+b row)  [6][64] = 6144
#define WS_INV   172032u     // inverse perm int[2*20480] = 163840
#define WS_XN    335872u     // xn bf16 [245760][128] = 62914560
#define WS_YF    63250432u   // y_f bf16 (pre-norm) = 62914560
#define WS_YB    126164992u  // y_b bf16 (pre-norm, pre-flipped) = 62914560

__device__ __forceinline__ float asf(unsigned int u){ float f; __builtin_memcpy(&f, &u, 4); return f; }
__device__ __forceinline__ int f2i(float f){ int i; __builtin_memcpy(&i, &f, 4); return i; }
__device__ __forceinline__ unsigned short f2bf(float f){
  unsigned int u; __builtin_memcpy(&u, &f, 4);
  unsigned int r = (u + 0x7fffu + ((u >> 16) & 1u)) >> 16;
  return (unsigned short)r;
}
__device__ __forceinline__ float fast_sigm(float x){ return __builtin_amdgcn_rcpf(1.0f + __expf(-x)); }
__device__ __forceinline__ float fast_tanh(float x){ return 1.0f - 2.0f * __builtin_amdgcn_rcpf(1.0f + __expf(2.0f * x)); }
__device__ __forceinline__ float fast_gelu(float v){
  float s = v * 0.70710678118654752f;
  float ax = fabsf(s);
  float t = __builtin_amdgcn_rcpf(1.0f + 0.3275911f * ax);
  float p = t * (0.254829592f + t * (-0.284496736f + t * (1.421413741f + t * (-1.453152027f + t * 1.061405429f))));
  float er = 1.0f - p * __expf(-ax * ax);
  er = (s < 0.0f) ? -er : er;
  return 0.5f * v * (1.0f + er);
}

// ---------------- K0: all weight prep -> bf16 MFMA B-fragments ----------------
__global__ __launch_bounds__(256) void k0_wprep(
    const float* __restrict__ win, const float* __restrict__ wout,
    const float* __restrict__ w1m, const float* __restrict__ w2m,
    const float* __restrict__ nwf, const float* __restrict__ nwb,
    const float* __restrict__ ew, const float* __restrict__ eb,
    const float* __restrict__ l1w, const float* __restrict__ l1b,
    const float* __restrict__ l2w, const float* __restrict__ l2b,
    unsigned char* __restrict__ ws)
{
  int gt = blockIdx.x * 256 + threadIdx.x;
  int g = gt >> 6, lane = gt & 63;
  int ln = lane & 15, kg = lane >> 4;
  union { unsigned short u[8]; short8 s; } cv;
  unsigned int dst; int gl;
  if (g < 68){
    gl = g; int nt = gl >> 2, kk = gl & 3;
    int n = nt * 16 + ln;
    #pragma unroll
    for (int j = 0; j < 8; j++){
      int k = kk * 32 + kg * 8 + j;
      cv.u[j] = f2bf((n < 266) ? win[(size_t)k * 266 + n] : 0.0f);
    }
    dst = WS_WIN;
  } else if (g < 116){
    int isb = (g >= 92); gl = g - (isb ? 92 : 68);
    int nt = gl >> 2, kk = gl & 3;
    int n = nt * 16 + ln;
    const float* nw = isb ? nwb : nwf;
    #pragma unroll
    for (int j = 0; j < 8; j++){
      int k = kk * 32 + kg * 8 + j;
      cv.u[j] = f2bf(0.5f * nw[k] * wout[(size_t)k * 96 + n]);
    }
    dst = isb ? WS_WOB : WS_WOF;
  } else if (g < 152){
    int is2 = (g >= 134); gl = g - (is2 ? 134 : 116);
    int nt = gl / 3, kk = gl % 3;
    int n = nt * 16 + ln;
    const float* src = is2 ? w2m : w1m;
    #pragma unroll
    for (int j = 0; j < 8; j++){
      int k = kk * 32 + kg * 8 + j;
      cv.u[j] = f2bf(src[(size_t)k * 96 + n]);
    }
    dst = is2 ? WS_W2 : WS_W1;
  } else if (g < 154){
    gl = g - 152; int n = gl * 16 + ln;
    #pragma unroll
    for (int j = 0; j < 8; j++){
      int k = kg * 8 + j;
      float f = (k < 28) ? ew[k * 32 + n] : ((k == 28) ? eb[n] : 0.0f);
      cv.u[j] = f2bf(f);
    }
    dst = WS_EW;
  } else if (g < 162){
    gl = g - 154; int n = gl * 16 + ln;
    #pragma unroll
    for (int j = 0; j < 8; j++){
      int k = kg * 8 + j;
      float f = (k < 8) ? l1w[k * 128 + n] : ((k == 8) ? l1b[n] : 0.0f);
      cv.u[j] = f2bf(f);
    }
    dst = WS_L1;
  } else {
    gl = g - 162; int n = gl * 16 + ln;
    #pragma unroll
    for (int j = 0; j < 8; j++){
      int k = kg * 8 + j;
      float f = (k < 8) ? l2w[k * 96 + n] : ((k == 8) ? l2b[n] : 0.0f);
      cv.u[j] = f2bf(f);
    }
    dst = WS_L2;
  }
  *(short8*)(ws + dst + (size_t)(gl * 64 + lane) * 16) = cv.s;
}

// ---------------- K0b: inverse permutation ----------------
__global__ __launch_bounds__(256) void k0b_inv(
    const int* __restrict__ curves, unsigned char* __restrict__ ws)
{
  int i = blockIdx.x * 256 + threadIdx.x;   // < 40960
  int p = i % PP;
  ((int*)(ws + WS_INV))[(i / PP) * PP + curves[i]] = p;
}

// ---------------- K1: SOURCE-ordered gather-free prep ----------------
__global__ __launch_bounds__(256) void k1_prep(
    const float* __restrict__ x, const float* __restrict__ xst,
    const float* __restrict__ xhr, unsigned char* __restrict__ ws)
{
  __shared__ unsigned short hrl[4][16][40];    // tanh(embed), bf16
  __shared__ unsigned short lol[4][16][136];   // tanh(loan1), bf16
  int tid = threadIdx.x, lane = tid & 63, w = tid >> 6;
  int pos0 = blockIdx.x * 64;
  int b = pos0 / (TT * PP); int r = pos0 % (TT * PP);
  int t = r / PP; int c0 = r % PP;
  size_t tbase = (size_t)(b * TT + t) * PP;

  // ---- phase A ----
  {
    int arow = w * 16 + (lane & 15);
    int g = lane >> 4;
    const float* hrow = xhr + (tbase + c0 + arow) * 28;
    float4 f0 = *(const float4*)(hrow + g * 8);
    float4 f1 = (g < 3) ? *(const float4*)(hrow + g * 8 + 4) : (float4){0.f,0.f,0.f,0.f};
    const float4* xsr = (const float4*)(xst + (tbase + c0 + arow) * 8);
    float4 s0 = xsr[0], s1 = xsr[1];
    union { unsigned short u[8]; short8 s; } ae, al;
    ae.u[0]=f2bf(f0.x); ae.u[1]=f2bf(f0.y); ae.u[2]=f2bf(f0.z); ae.u[3]=f2bf(f0.w);
    ae.u[4]=f2bf(f1.x); ae.u[5]=f2bf(f1.y); ae.u[6]=f2bf(f1.z); ae.u[7]=f2bf(f1.w);
    if (g == 3){ ae.u[4] = 0x3F80u; ae.u[5]=0; ae.u[6]=0; ae.u[7]=0; }
    #pragma unroll
    for (int j = 0; j < 8; j++) al.u[j] = 0;
    if (g == 0){
      al.u[0]=f2bf(s0.x); al.u[1]=f2bf(s0.y); al.u[2]=f2bf(s0.z); al.u[3]=f2bf(s0.w);
      al.u[4]=f2bf(s1.x); al.u[5]=f2bf(s1.y); al.u[6]=f2bf(s1.z); al.u[7]=f2bf(s1.w);
    } else if (g == 1){ al.u[0] = 0x3F80u; }
    const short8* BE = (const short8*)(ws + WS_EW);
    const short8* BL = (const short8*)(ws + WS_L1);
    f32x4 he0 = {0.f,0.f,0.f,0.f}, he1 = {0.f,0.f,0.f,0.f};
    he0 = __builtin_amdgcn_mfma_f32_16x16x32_bf16(ae.s, BE[lane], he0, 0, 0, 0);
    he1 = __builtin_amdgcn_mfma_f32_16x16x32_bf16(ae.s, BE[64 + lane], he1, 0, 0, 0);
    f32x4 lo[8];
    #pragma unroll
    for (int nt = 0; nt < 8; nt++){
      f32x4 z = {0.f,0.f,0.f,0.f};
      lo[nt] = __builtin_amdgcn_mfma_f32_16x16x32_bf16(al.s, BL[nt * 64 + lane], z, 0, 0, 0);
    }
    int rl = (lane >> 4) * 4, col = lane & 15;
    #pragma unroll
    for (int r2 = 0; r2 < 4; r2++){
      hrl[w][rl + r2][col]      = f2bf(fast_tanh(he0[r2]));
      hrl[w][rl + r2][16 + col] = f2bf(fast_tanh(he1[r2]));
    }
    #pragma unroll
    for (int nt = 0; nt < 8; nt++){
      #pragma unroll
      for (int r2 = 0; r2 < 4; r2++)
        lol[w][rl + r2][nt * 16 + col] = f2bf(fast_tanh(lo[nt][r2]));
    }
  }
  __syncthreads();

  // ---- phase B ----
  int pp = tid >> 2, q = tid & 3;
  int c = c0 + pp;
  union { float4 v4[8]; float v[32]; } xv;
  if (q < 3){
    const float4* xr4 = (const float4*)(x + (tbase + c) * 96 + q * 32);
    #pragma unroll
    for (int j = 0; j < 8; j++) xv.v4[j] = xr4[j];
  } else {
    const u32x4* hp = (const u32x4*)(&hrl[pp >> 4][pp & 15][0]);
    #pragma unroll
    for (int j = 0; j < 4; j++){
      u32x4 hv = hp[j];
      #pragma unroll
      for (int e = 0; e < 4; e++){
        unsigned int u = hv[e];
        xv.v[j*8 + e*2]     = asf(u << 16);
        xv.v[j*8 + e*2 + 1] = asf(u & 0xffff0000u);
      }
    }
  }
  float s = 0.f, s2 = 0.f;
  #pragma unroll
  for (int j = 0; j < 32; j++){ float v = xv.v[j]; s += v; s2 += v * v; }
  s += __shfl_xor(s, 1); s2 += __shfl_xor(s2, 1);
  s += __shfl_xor(s, 2); s2 += __shfl_xor(s2, 2);
  float mu = s * (1.0f / 128.0f);
  float rs = __builtin_amdgcn_rsqf(s2 * (1.0f / 128.0f) - mu * mu + EPSc);

  int p = ((const int*)(ws + WS_INV))[b * PP + c];
  const u32x4* lp = (const u32x4*)(&lol[pp >> 4][pp & 15][q * 32]);
  u32x4* dst = (u32x4*)((unsigned short*)(ws + WS_XN) + (tbase + p) * 128 + q * 32);
  #pragma unroll
  for (int j = 0; j < 4; j++){
    u32x4 lv = lp[j];
    unsigned int pk[4];
    #pragma unroll
    for (int e = 0; e < 4; e++){
      unsigned int lu = lv[e];
      float l0 = asf(lu << 16), l1 = asf(lu & 0xffff0000u);
      int idx = j*8 + e*2;
      float r0 = (xv.v[idx]   - mu) * rs + l0;
      float r1 = (xv.v[idx+1] - mu) * rs + l1;
      asm("v_cvt_pk_bf16_f32 %0, %1, %2" : "=v"(pk[e]) : "v"(r0), "v"(r1));
    }
    u32x4 stv = { pk[0], pk[1], pk[2], pk[3] };
    dst[j] = stv;
  }
}

// row index within the tile for scan step s (bwd reads reversed cells)
__device__ __forceinline__ int urow_of(int s, int dir){
  int g0 = (s >= 20) ? 2 : ((s >= 10) ? 1 : 0);
  int g1 = s - g0 * 10;
  return dir ? (g0 * 10 + 9 - g1) : s;
}

// ---------------- K2: fused in_proj MFMA + bidirectional Mamba scan ----------------
#define ULDS 276   // row stride in u16 (552 B = 138 dwords, 138%32=10 -> conflict-free group shift)
__global__ __launch_bounds__(256, 4) void k2_mamba(
    unsigned char* __restrict__ ws,
    const float* __restrict__ cwf, const float* __restrict__ cbf,
    const float* __restrict__ dtbf, const float* __restrict__ alf,
    const float* __restrict__ Dpf,
    const float* __restrict__ cwb, const float* __restrict__ cbb,
    const float* __restrict__ dtbb, const float* __restrict__ alb,
    const float* __restrict__ Dpb)
{
  __shared__ unsigned short uld[2][30][ULDS];
  int blk = blockIdx.x;
  int b = blk >> 11; int tb = (blk >> 10) & 1; int pbh = blk & 1023;
  int wid = threadIdx.x >> 6, lane = threadIdx.x & 63;
  int pairIdx = wid >> 1, dir = wid & 1;
  int pb = pbh * 2 + pairIdx;

  // --- phase 1: u = xn @ W_in via MFMA ---
  const unsigned short* xn = (const unsigned short*)(ws + WS_XN);
  int lr = dir * 16 + (lane & 15); if (lr > 29) lr = 29;
  int g0r = lr / 10, g1r = lr - g0r * 10;
  const unsigned short* arow = xn + (((size_t)(b * TT + tb * 3 + g0r) * PP) + (size_t)pb * 10 + g1r) * 128 + (lane >> 4) * 8;
  short8 afr[4];
  #pragma unroll
  for (int kk = 0; kk < 4; kk++) afr[kk] = *(const short8*)(arow + kk * 32);
  const short8* bbm = (const short8*)(ws + WS_WIN);
  int row0 = dir * 16 + (lane >> 4) * 4;
  int col0 = lane & 15;
  #pragma unroll
  for (int half = 0; half < 2; half++){
    const int n0 = half ? 9 : 0;
    const int cnt = half ? 8 : 9;
    f32x4 acc[9];
    #pragma unroll
    for (int i = 0; i < 9; i++) acc[i] = (f32x4){0.f,0.f,0.f,0.f};
    #pragma unroll
    for (int kk = 0; kk < 4; kk++){
      #pragma unroll
      for (int j = 0; j < 9; j++){
        if (j < cnt){
          short8 bf = bbm[((n0 + j) * 4 + kk) * 64 + lane];
          acc[j] = __builtin_amdgcn_mfma_f32_16x16x32_bf16(afr[kk], bf, acc[j], 0, 0, 0);
        }
      }
    }
    #pragma unroll
    for (int j = 0; j < 9; j++){
      if (j < cnt){
        int col = (n0 + j) * 16 + col0;
        #pragma unroll
        for (int r2 = 0; r2 < 4; r2++){
          int row = row0 + r2;
          if (row < 30 && col < 266) uld[pairIdx][row][col] = f2bf(acc[j][r2]);
        }
      }
    }
  }
  __syncthreads();

  // --- per-direction parameters ---
  const float* cw  = dir ? cwb  : cwf;
  const float* cb  = dir ? cbb  : cbf;
  const float* dtb = dir ? dtbb : dtbf;
  const float* al  = dir ? alb  : alf;
  const float* Dp  = dir ? Dpb  : Dpf;
  unsigned int* ybuf = (unsigned int*)(ws + (dir ? WS_YB : WS_YF));
  int pbown = dir ? (2047 - pb) : pb;
  int cbase = (tb * 1024 + (pbown >> 1)) * 6 + (pbown & 1);
  unsigned int wbase = (unsigned int)b * 7864320u + (unsigned int)lane;
  const unsigned short* tile = &uld[pairIdx][0][0];

  int c0 = lane * 2;
  int hh = lane >> 3;
  float w00=cw[c0*3+0], w01=cw[c0*3+1], w02=cw[c0*3+2], cb0=cb[c0];
  float w10=cw[c0*3+3], w11=cw[c0*3+4], w12=cw[c0*3+5], cb1=cb[c0+1];
  float wB0=cw[128*3+0], wB1=cw[128*3+1], wB2=cw[128*3+2], cbB=cb[128];
  float wC0=cw[129*3+0], wC1=cw[129*3+1], wC2=cw[129*3+2], cbC=cb[129];
  float Dh = Dp[hh];

  // --- phase 2a: precompute dA(l,h), sB(l,h), Cv(l) ---
  float dAc[4], sBc[4], Cvc[4];
  {
    int h2 = lane & 7;
    int lrow = lane >> 3;
    float dtb2 = dtb[h2];
    float Ah2 = -__expf(al[h2]);
    #pragma unroll
    for (int cci = 0; cci < 4; cci++){
      int l = cci * 8 + lrow; if (l > 29) l = 29;
      float Braw[3], Craw[3];
      #pragma unroll
      for (int tap = 0; tap < 3; tap++){
        int sp = l - tap;
        if (sp >= 0){
          unsigned int wv = *(const unsigned int*)(tile + urow_of(sp, dir) * ULDS + 256);
          Braw[tap] = asf(wv << 16);
          Craw[tap] = asf(wv & 0xffff0000u);
        } else { Braw[tap] = 0.f; Craw[tap] = 0.f; }
      }
      float Bcc = fmaf(wB2, Braw[0], fmaf(wB1, Braw[1], fmaf(wB0, Braw[2], cbB)));
      float Ccc = fmaf(wC2, Craw[0], fmaf(wC1, Craw[1], fmaf(wC0, Craw[2], cbC)));
      float Bvv = Bcc * fast_sigm(Bcc);
      Cvc[cci]  = Ccc * fast_sigm(Ccc);
      float dtr = asf((unsigned int)tile[urow_of(l, dir) * ULDS + 258 + h2] << 16);
      float dtx = dtr + dtb2;
      float e = __expf(-fabsf(dtx));
      float dt = fmaxf(dtx, 0.0f) + __logf(1.0f + e);
      dAc[cci] = __expf(dt * Ah2);
      sBc[cci] = dt * Bvv;
    }
  }

  // --- phase 2b: scan ---
  int vbase = (lane >> 3) << 2;   // bpermute lane-group base (bytes)
  float xp10=0,xp20=0,xp11=0,xp21=0;
  float h0=0.f, h1=0.f;
  #pragma unroll
  for (int l = 0; l < 30; l++){
    const int Kl = (l/3)*12288 + (l%3)*2;
    const int Kd = Kl / 20480, Km = Kl % 20480;
    const int urow_b = (l/10)*10 + 9 - (l%10);
    const unsigned short* ur = tile + (dir ? urow_b : l) * ULDS;
    unsigned int zz = *(const unsigned int*)(ur + c0);
    unsigned int xx = *(const unsigned int*)(ur + 128 + c0);
    const int chn = l >> 3, rrl = l & 7;
    float dA = asf((unsigned int)__builtin_amdgcn_ds_bpermute(vbase + (rrl << 5), f2i(dAc[chn])));
    float sB = asf((unsigned int)__builtin_amdgcn_ds_bpermute(vbase + (rrl << 5), f2i(sBc[chn])));
    float Cv = asf((unsigned int)__builtin_amdgcn_readlane(f2i(Cvc[chn]), rrl * 8));
    float z0 = asf(zz << 16), z1 = asf(zz & 0xffff0000u);
    float xr0 = asf(xx << 16), xr1 = asf(xx & 0xffff0000u);
    float xc0 = fmaf(w02, xr0, fmaf(w01, xp10, fmaf(w00, xp20, cb0)));
    float xc1 = fmaf(w12, xr1, fmaf(w11, xp11, fmaf(w10, xp21, cb1)));
    xp20=xp10; xp10=xr0; xp21=xp11; xp11=xr1;
    float xh0 = xc0 * fast_sigm(xc0), xh1 = xc1 * fast_sigm(xc1);
    h0 = fmaf(h0, dA, xh0 * sB);
    h1 = fmaf(h1, dA, xh1 * sB);
    float y0 = fmaf(h0, Cv, xh0 * Dh) * (z0 * fast_sigm(z0));
    float y1 = fmaf(h1, Cv, xh1 * Dh) * (z1 * fast_sigm(z1));
    unsigned int pk;
    asm("v_cvt_pk_bf16_f32 %0, %1, %2" : "=v"(pk) : "v"(y0), "v"(y1));
    int pD = Km + cbase, tD = Kd;
    if (pD >= 20480){ pD -= 20480; tD++; }
    if (dir) pD = 20479 - pD;
    ybuf[wbase + (unsigned int)tD * 1310720u + (unsigned int)pD * 64u] = pk;
  }
}

// ---------------- K3: fused epilogue — y direct-to-register A-frags, barrier-free ----------------
// Wave w owns rows w*16..w*16+15 exclusively (LDS t1/gelu buffer is wave-private rows);
// no __syncthreads needed. yf/yb loaded straight into MFMA A-frag layout from global,
// RMS via 2 shfl_xor across the 4 ag-lanes of each colA.
__global__ __launch_bounds__(256) void k3_epi(
    const unsigned char* __restrict__ ws,
    const float* __restrict__ x, const float* __restrict__ xst,
    const int* __restrict__ curves,
    const float* __restrict__ b1, const float* __restrict__ b2,
    float* __restrict__ out)
{
  __shared__ unsigned short Abuf[64 * 128];   // 16 KB: t1 then gelu (swizzled, wave-private rows)
  int tid = threadIdx.x; int lane = tid & 63; int w = tid >> 6;
  int pos0 = blockIdx.x * 64;
  int b = pos0 / (TT * PP); int rm = pos0 % (TT * PP);
  int t = rm / PP; int p0 = rm % PP;
  size_t tbase = (size_t)(b * TT + t) * PP;
  const int* cur = curves + b * PP;
  unsigned char* b0 = (unsigned char*)(&Abuf[0]);

  int colA = lane & 15, ag = lane >> 4;
  int arow = w * 16 + colA;
  int crow0 = w * 16 + ag * 4;

  // ---- early VMEM: yf/yb A-frag rows, gathered residual x, gathered xs ----
  u32x4 yfv[4], ybv[4];
  {
    const u32x4* yf4 = (const u32x4*)(ws + WS_YF) + (size_t)(pos0 + arow) * 16 + ag;
    const u32x4* yb4 = (const u32x4*)(ws + WS_YB) + (size_t)(pos0 + arow) * 16 + ag;
    #pragma unroll
    for (int kk = 0; kk < 4; kk++){ yfv[kk] = yf4[kk * 4]; ybv[kk] = yb4[kk * 4]; }
  }
  float xres[6][4];
  #pragma unroll
  for (int r2 = 0; r2 < 4; r2++){
    int cp = cur[p0 + crow0 + r2];
    const float* xr = x + (tbase + cp) * 96;
    #pragma unroll
    for (int nt = 0; nt < 6; nt++) xres[nt][r2] = xr[nt * 16 + colA];
  }
  union { unsigned short u[8]; short8 s; } al;
  {
    int cpa = cur[p0 + arow];
    const float4* xsr = (const float4*)(xst + (tbase + cpa) * 8);
    float4 s0 = xsr[0], s1 = xsr[1];
    #pragma unroll
    for (int j = 0; j < 8; j++) al.u[j] = 0;
    if (ag == 0){
      al.u[0]=f2bf(s0.x); al.u[1]=f2bf(s0.y); al.u[2]=f2bf(s0.z); al.u[3]=f2bf(s0.w);
      al.u[4]=f2bf(s1.x); al.u[5]=f2bf(s1.y); al.u[6]=f2bf(s1.z); al.u[7]=f2bf(s1.w);
    } else if (ag == 1){ al.u[0] = 0x3F80u; }
  }

  // ---- RMS of yf/yb rows (4 ag-lanes of same colA hold all 128 ch) ----
  float ssf = 0.f, ssb = 0.f;
  #pragma unroll
  for (int kk = 0; kk < 4; kk++){
    #pragma unroll
    for (int e = 0; e < 4; e++){
      unsigned int uf = yfv[kk][e], ub = ybv[kk][e];
      float a0 = asf(uf << 16), a1 = asf(uf & 0xffff0000u);
      float c0v = asf(ub << 16), c1v = asf(ub & 0xffff0000u);
      ssf += a0*a0 + a1*a1; ssb += c0v*c0v + c1v*c1v;
    }
  }
  ssf += __shfl_xor(ssf, 16); ssb += __shfl_xor(ssb, 16);
  ssf += __shfl_xor(ssf, 32); ssb += __shfl_xor(ssb, 32);
  float rf = __builtin_amdgcn_rsqf(ssf * (1.0f/128.0f) + EPSc);
  float rb = __builtin_amdgcn_rsqf(ssb * (1.0f/128.0f) + EPSc);
  union { unsigned int u[4]; short8 s; } aff[4], abb[4];
  #pragma unroll
  for (int kk = 0; kk < 4; kk++){
    #pragma unroll
    for (int e = 0; e < 4; e++){
      unsigned int uf = yfv[kk][e], ub = ybv[kk][e];
      float a0 = asf(uf << 16) * rf, a1 = asf(uf & 0xffff0000u) * rf;
      float c0v = asf(ub << 16) * rb, c1v = asf(ub & 0xffff0000u) * rb;
      asm("v_cvt_pk_bf16_f32 %0, %1, %2" : "=v"(aff[kk].u[e]) : "v"(a0), "v"(a1));
      asm("v_cvt_pk_bf16_f32 %0, %1, %2" : "=v"(abb[kk].u[e]) : "v"(c0v), "v"(c1v));
    }
  }

  // ---- stage 1: X1 = yf_n@Woutf + yb_n@Woutb + xg ; LN ; t1 -> LDS ----
  f32x4 acc[6], accl[6];
  #pragma unroll
  for (int i = 0; i < 6; i++){ acc[i] = (f32x4){0.f,0.f,0.f,0.f}; accl[i] = (f32x4){0.f,0.f,0.f,0.f}; }
  {
    const short8* WF = (const short8*)(ws + WS_WOF);
    const short8* WB = (const short8*)(ws + WS_WOB);
    #pragma unroll
    for (int kk = 0; kk < 4; kk++){
      #pragma unroll
      for (int nt = 0; nt < 6; nt++){
        acc[nt] = __builtin_amdgcn_mfma_f32_16x16x32_bf16(aff[kk].s, WF[(nt*4+kk)*64 + lane], acc[nt], 0, 0, 0);
        acc[nt] = __builtin_amdgcn_mfma_f32_16x16x32_bf16(abb[kk].s, WB[(nt*4+kk)*64 + lane], acc[nt], 0, 0, 0);
      }
    }
    const short8* WL = (const short8*)(ws + WS_L2);
    #pragma unroll
    for (int nt = 0; nt < 6; nt++)
      accl[nt] = __builtin_amdgcn_mfma_f32_16x16x32_bf16(al.s, WL[nt*64 + lane], accl[nt], 0, 0, 0);
  }
  float X1[6][4];
  #pragma unroll
  for (int nt = 0; nt < 6; nt++)
    #pragma unroll
    for (int r2 = 0; r2 < 4; r2++) X1[nt][r2] = acc[nt][r2] + xres[nt][r2];
  float mu[4], rsv[4];
  {
    float sA[4], sQ[4];
    #pragma unroll
    for (int r2 = 0; r2 < 4; r2++){
      float s = 0.f, s2 = 0.f;
      #pragma unroll
      for (int nt = 0; nt < 6; nt++){ float v = X1[nt][r2]; s += v; s2 += v * v; }
      sA[r2] = s; sQ[r2] = s2;
    }
    #pragma unroll
    for (int m = 1; m < 16; m <<= 1){
      #pragma unroll
      for (int r2 = 0; r2 < 4; r2++){ sA[r2] += __shfl_xor(sA[r2], m); sQ[r2] += __shfl_xor(sQ[r2], m); }
    }
    #pragma unroll
    for (int r2 = 0; r2 < 4; r2++){
      mu[r2] = sA[r2] * (1.0f / 96.0f);
      rsv[r2] = __builtin_amdgcn_rsqf(sQ[r2] * (1.0f / 96.0f) - mu[r2] * mu[r2] + EPSc);
    }
  }
  #pragma unroll
  for (int nt = 0; nt < 6; nt++){
    #pragma unroll
    for (int r2 = 0; r2 < 4; r2++){
      float tv = (X1[nt][r2] - mu[r2]) * rsv[r2] + fast_tanh(accl[nt][r2]);
      int crow = crow0 + r2, n = nt * 16 + colA;
      *(unsigned short*)(b0 + crow * 256 + ((n * 2) ^ ((crow & 7) << 4))) = f2bf(tv);
    }
  }

  // ---- stage 2: gelu(t1 @ W1 + b1) -> LDS (wave-private rows, DS in-order; no barrier) ----
  f32x4 acc2[6];
  #pragma unroll
  for (int i = 0; i < 6; i++) acc2[i] = (f32x4){0.f,0.f,0.f,0.f};
  {
    unsigned int rmask = (unsigned int)((arow & 7) << 4);
    const short8* W1f = (const short8*)(ws + WS_W1);
    #pragma unroll
    for (int kk = 0; kk < 3; kk++){
      int offc = arow * 256 + (int)(((unsigned)(kk * 64 + ag * 16)) ^ rmask);
      short8 af = *(const short8*)(b0 + offc);
      #pragma unroll
      for (int nt = 0; nt < 6; nt++)
        acc2[nt] = __builtin_amdgcn_mfma_f32_16x16x32_bf16(af, W1f[(nt*3+kk)*64 + lane], acc2[nt], 0, 0, 0);
    }
  }
  #pragma unroll
  for (int nt = 0; nt < 6; nt++){
    float bv = b1[nt * 16 + colA];
    #pragma unroll
    for (int r2 = 0; r2 < 4; r2++){
      float g = fast_gelu(acc2[nt][r2] + bv);
      int crow = crow0 + r2, n = nt * 16 + colA;
      *(unsigned short*)(b0 + crow * 256 + ((n * 2) ^ ((crow & 7) << 4))) = f2bf(g);
    }
  }

  // ---- stage 3: out = gelu @ W2 + b2 + X1 ----
  f32x4 acc3[6];
  #pragma unroll
  for (int i = 0; i < 6; i++) acc3[i] = (f32x4){0.f,0.f,0.f,0.f};
  {
    unsigned int rmask = (unsigned int)((arow & 7) << 4);
    const short8* W2f = (const short8*)(ws + WS_W2);
    #pragma unroll
    for (int kk = 0; kk < 3; kk++){
      int offc = arow * 256 + (int)(((unsigned)(kk * 64 + ag * 16)) ^ rmask);
      short8 af = *(const short8*)(b0 + offc);
      #pragma unroll
      for (int nt = 0; nt < 6; nt++)
        acc3[nt] = __builtin_amdgcn_mfma_f32_16x16x32_bf16(af, W2f[(nt*3+kk)*64 + lane], acc3[nt], 0, 0, 0);
    }
  }
  #pragma unroll
  for (int r2 = 0; r2 < 4; r2++){
    int crow = crow0 + r2;
    size_t ob = (tbase + p0 + crow) * 96;
    #pragma unroll
    for (int nt = 0; nt < 6; nt++){
      int n = nt * 16 + colA;
      out[ob + n] = acc3[nt][r2] + b2[n] + X1[nt][r2];
    }
  }
}

extern "C" void kernel_launch(void* const* d_in, const int* in_sizes, int n_in,
                              void* d_out, int out_size, void* d_ws, size_t ws_size,
                              hipStream_t stream)
{
  const float* x     = (const float*)d_in[0];
  const float* xst   = (const float*)d_in[1];
  const float* xhr   = (const float*)d_in[2];
  const int*   curves= (const int*)d_in[3];
  const float* embw  = (const float*)d_in[4];
  const float* embb  = (const float*)d_in[5];
  const float* l1w   = (const float*)d_in[6];
  const float* l1b   = (const float*)d_in[7];
  const float* l2w   = (const float*)d_in[8];
  const float* l2b   = (const float*)d_in[9];
  const float* winp  = (const float*)d_in[10];
  const float* cwf   = (const float*)d_in[11];
  const float* cbf   = (const float*)d_in[12];
  const float* dtbf  = (const float*)d_in[13];
  const float* alf   = (const float*)d_in[14];
  const float* Df    = (const float*)d_in[15];
  const float* nwf   = (const float*)d_in[16];
  const float* cwb   = (const float*)d_in[17];
  const float* cbb   = (const float*)d_in[18];
  const float* dtbb  = (const float*)d_in[19];
  const float* alb   = (const float*)d_in[20];
  const float* Db    = (const float*)d_in[21];
  const float* nwb   = (const float*)d_in[22];
  const float* wout  = (const float*)d_in[23];
  const float* w1    = (const float*)d_in[24];
  const float* b1    = (const float*)d_in[25];
  const float* w2    = (const float*)d_in[26];
  const float* b2    = (const float*)d_in[27];
  unsigned char* ws  = (unsigned char*)d_ws;

  k0_wprep<<<42, 256, 0, stream>>>(winp, wout, w1, w2, nwf, nwb,
                                   embw, embb, l1w, l1b, l2w, l2b, ws);
  k0b_inv<<<160, 256, 0, stream>>>(curves, ws);
  k1_prep<<<3840, 256, 0, stream>>>(x, xst, xhr, ws);
  k2_mamba<<<4096, 256, 0, stream>>>(ws, cwf, cbf, dtbf, alf, Df,
                                         cwb, cbb, dtbb, alb, Db);
  k3_epi<<<3840, 256, 0, stream>>>(ws, x, xst, curves, b1, b2, (float*)d_out);
}